// Round 9
// baseline (2020.131 us; speedup 1.0000x reference)
//
#include <hip/hip_runtime.h>
#include <math.h>

#define EPS 1e-8f

constexpr int N_USERS = 6000;
constexpr int N_ITEMS = 4000;
constexpr int NU_P = 6016;  // 47 * 128
constexpr int NI_P = 4096;  // 32 * 128

typedef __bf16 bf16_8 __attribute__((ext_vector_type(8)));
typedef float f32_4 __attribute__((ext_vector_type(4)));
typedef int i32x4 __attribute__((ext_vector_type(4)));

// ---------------------------------------------------------------------------
__device__ __forceinline__ void stage16(const void* g, void* l) {
  __builtin_amdgcn_global_load_lds(
      (const __attribute__((address_space(1))) void*)g,
      (__attribute__((address_space(3))) void*)l, 16, 0, 0);
}

// XCD-aware bijective swizzle (requires nwg % 8 == 0; all MFMA grids are).
__device__ __forceinline__ int xcd_swz(int p, int nwg) {
  return (p & 7) * (nwg >> 3) + (p >> 3);
}

// triangular decode: p -> (by, bx) with bx <= by
__device__ __forceinline__ void tri_decode(int p, int& by, int& bx) {
  int r = (int)((sqrtf(8.f * p + 1.f) - 1.f) * 0.5f);
  while ((r + 1) * (r + 2) / 2 <= p) r++;
  while (r * (r + 1) / 2 > p) r--;
  by = r;
  bx = p - r * (r + 1) / 2;
}

// grouped decode (G=8 rows, column-major within band) for L2 locality
__device__ __forceinline__ void grp_decode(int p, int nby, int nbx, int& by,
                                           int& bx) {
  const int G = 8;
  const int wide = G * nbx;
  const int band = p / wide;
  const int rem = p - band * wide;
  const int h = min(G, nby - band * G);
  by = band * G + rem % h;
  bx = rem / h;
}

// ---------------------------------------------------------------------------
// bf16 prop GEMM, C[M,N] = A @ B^T, compile-time K/strides.
// UNROLLED 2-DEEP PREFETCH, STATIC BUFFER INDICES: the K-loop is manually
// unrolled by two chunks so every stage/compute uses a LITERAL buffer index
// (round-8's runtime `cur` forced per-iteration address recompute -> VALU 53%;
// round-7's stage->barrier->compute exposed full load latency). Pattern:
//   stage(b1,k) ; compute(b0) ; bar ; stage(b0,k+32) ; compute(b1) ; bar
// Loads overlap MFMA; barrier's vmcnt(0) drain completes the prefetch; each
// buffer's re-stage is separated from its last read by a barrier (race-free).
// Data/MFMA order identical to verified r6/r7/r8 -> bit-identical output.
// ---------------------------------------------------------------------------
template <int KK, int LDA, int LDB, int LDC, int OUTBF16>
__global__ __launch_bounds__(256) void mfma_prop_bf16(
    const __bf16* __restrict__ A, const __bf16* __restrict__ B,
    float* __restrict__ Cf, __bf16* __restrict__ Cb, int M, int N, int nby,
    int nbx) {
  __shared__ __bf16 sA[2][128 * 32];
  __shared__ __bf16 sB[2][128 * 32];

  int by, bx;
  grp_decode(xcd_swz(blockIdx.x, gridDim.x), nby, nbx, by, bx);

  const int tid = threadIdx.x;
  const int lane = tid & 63;
  const int wave = tid >> 6;
  const int wm = (wave >> 1) * 64;
  const int wn = (wave & 1) * 64;
  const int lm = lane & 15;
  const int kg = lane >> 4;
  const long row0 = (long)by * 128;
  const long col0 = (long)bx * 128;

  f32_4 acc[4][4];
#pragma unroll
  for (int i = 0; i < 4; i++)
#pragma unroll
    for (int j = 0; j < 4; j++) acc[i][j] = (f32_4){0.f, 0.f, 0.f, 0.f};

  const int c0 = tid, c1 = tid + 256;
  const int r0c = c0 >> 2, j0c = ((c0 & 3) - (r0c >> 1)) & 3;
  const int r1c = c1 >> 2, j1c = ((c1 & 3) - (r1c >> 1)) & 3;

  // loop-invariant fragment offsets (elements)
  int offA[4], offB[4];
#pragma unroll
  for (int i = 0; i < 4; i++) {
    const int ra = wm + i * 16 + lm;
    const int rb = wn + i * 16 + lm;
    offA[i] = (ra * 4 + ((kg + (ra >> 1)) & 3)) * 8;
    offB[i] = (rb * 4 + ((kg + (rb >> 1)) & 3)) * 8;
  }

  const __bf16* a0 = A + (row0 + r0c) * LDA + j0c * 8;
  const __bf16* a1 = A + (row0 + r1c) * LDA + j1c * 8;
  const __bf16* b0 = B + (col0 + r0c) * LDB + j0c * 8;
  const __bf16* b1 = B + (col0 + r1c) * LDB + j1c * 8;

#define PROP_STAGE(BUF, K0)                  \
  do {                                       \
    stage16(a0 + (K0), &sA[BUF][c0 * 8]);    \
    stage16(a1 + (K0), &sA[BUF][c1 * 8]);    \
    stage16(b0 + (K0), &sB[BUF][c0 * 8]);    \
    stage16(b1 + (K0), &sB[BUF][c1 * 8]);    \
  } while (0)

#define PROP_COMPUTE(BUF)                                                   \
  do {                                                                      \
    bf16_8 a[4], b[4];                                                      \
    _Pragma("unroll") for (int i = 0; i < 4; i++) {                         \
      a[i] = *(const bf16_8*)&sA[BUF][offA[i]];                             \
      b[i] = *(const bf16_8*)&sB[BUF][offB[i]];                             \
    }                                                                       \
    _Pragma("unroll") for (int i = 0; i < 4; i++) _Pragma("unroll") for (   \
        int j = 0; j < 4; j++) acc[i][j] =                                  \
        __builtin_amdgcn_mfma_f32_16x16x32_bf16(a[i], b[j], acc[i][j], 0,   \
                                                0, 0);                      \
  } while (0)

  PROP_STAGE(0, 0);
  __syncthreads();
  // KK/32 chunks, even count; pairs {k0, k0+32} staged while computing
  // {k0-32, k0}.
  for (int k0 = 32; k0 < KK - 32; k0 += 64) {
    PROP_STAGE(1, k0);
    PROP_COMPUTE(0);
    __syncthreads();
    PROP_STAGE(0, k0 + 32);
    PROP_COMPUTE(1);
    __syncthreads();
  }
  PROP_STAGE(1, KK - 32);
  PROP_COMPUTE(0);
  __syncthreads();
  PROP_COMPUTE(1);

#undef PROP_STAGE
#undef PROP_COMPUTE

  // epilogue: C/D layout col=lane&15, row=(lane>>4)*4+reg
#pragma unroll
  for (int i = 0; i < 4; i++)
#pragma unroll
    for (int j = 0; j < 4; j++)
#pragma unroll
      for (int r = 0; r < 4; r++) {
        const long gm = row0 + wm + i * 16 + kg * 4 + r;
        const long gn = col0 + wn + j * 16 + lm;
        if (gm < M && gn < N) {
          if (OUTBF16)
            Cb[gm * LDC + gn] = (__bf16)acc[i][j][r];
          else
            Cf[gm * LDC + gn] = acc[i][j][r];
        }
      }
}

// ---------------------------------------------------------------------------
// Single-plane centered-i8 GRAM (math verified r3/r6), compile-time K/strides,
// same unrolled 2-deep prefetch with static buffer indices (BK=64 chunks;
// chunk counts 64 and 94, both even). LDS 32 KB as r8.
// ---------------------------------------------------------------------------
template <int KK, int LD, int LDC>
__global__ __launch_bounds__(256) void mfma_gram_i8(
    const signed char* __restrict__ Q, const float* __restrict__ sv,
    float* __restrict__ C, int Nn, float negq) {
  __shared__ signed char sA[2][128 * 64];
  __shared__ signed char sB[2][128 * 64];

  int by, bx;
  tri_decode(xcd_swz(blockIdx.x, gridDim.x), by, bx);

  const int tid = threadIdx.x;
  const int lane = tid & 63;
  const int wave = tid >> 6;
  const int wm = (wave >> 1) * 64;
  const int wn = (wave & 1) * 64;
  const int lm = lane & 15;
  const int kg = lane >> 4;
  const long row0 = (long)by * 128;
  const long col0 = (long)bx * 128;
  const float scale = 1.f / (254.f * 254.f);

  i32x4 acc[4][4];
#pragma unroll
  for (int i = 0; i < 4; i++)
#pragma unroll
    for (int j = 0; j < 4; j++) acc[i][j] = (i32x4){0, 0, 0, 0};

  const int c0 = tid, c1 = tid + 256;
  const int r0c = c0 >> 2, j0c = ((c0 & 3) - (r0c >> 1)) & 3;
  const int r1c = c1 >> 2, j1c = ((c1 & 3) - (r1c >> 1)) & 3;

  int offA[4], offB[4];
#pragma unroll
  for (int i = 0; i < 4; i++) {
    const int ra = wm + i * 16 + lm;
    const int rb = wn + i * 16 + lm;
    offA[i] = (ra * 4 + ((kg + (ra >> 1)) & 3)) * 16;
    offB[i] = (rb * 4 + ((kg + (rb >> 1)) & 3)) * 16;
  }

  const signed char* a0 = Q + (row0 + r0c) * LD + j0c * 16;
  const signed char* a1 = Q + (row0 + r1c) * LD + j1c * 16;
  const signed char* b0 = Q + (col0 + r0c) * LD + j0c * 16;
  const signed char* b1 = Q + (col0 + r1c) * LD + j1c * 16;

#define GRAM_STAGE(BUF, K0)                   \
  do {                                        \
    stage16(a0 + (K0), &sA[BUF][c0 * 16]);    \
    stage16(a1 + (K0), &sA[BUF][c1 * 16]);    \
    stage16(b0 + (K0), &sB[BUF][c0 * 16]);    \
    stage16(b1 + (K0), &sB[BUF][c1 * 16]);    \
  } while (0)

#define GRAM_COMPUTE(BUF)                                                 \
  do {                                                                    \
    i32x4 a[4], b[4];                                                     \
    _Pragma("unroll") for (int i = 0; i < 4; i++) {                       \
      a[i] = *(const i32x4*)&sA[BUF][offA[i]];                            \
      b[i] = *(const i32x4*)&sB[BUF][offB[i]];                            \
    }                                                                     \
    _Pragma("unroll") for (int i = 0; i < 4; i++) _Pragma("unroll") for ( \
        int j = 0; j < 4; j++) acc[i][j] =                                \
        __builtin_amdgcn_mfma_i32_16x16x64_i8(a[i], b[j], acc[i][j], 0,   \
                                              0, 0);                      \
  } while (0)

  GRAM_STAGE(0, 0);
  __syncthreads();
  for (int k0 = 64; k0 < KK - 64; k0 += 128) {
    GRAM_STAGE(1, k0);
    GRAM_COMPUTE(0);
    __syncthreads();
    GRAM_STAGE(0, k0 + 64);
    GRAM_COMPUTE(1);
    __syncthreads();
  }
  GRAM_STAGE(1, KK - 64);
  GRAM_COMPUTE(0);
  __syncthreads();
  GRAM_COMPUTE(1);

#undef GRAM_STAGE
#undef GRAM_COMPUTE

#pragma unroll
  for (int i = 0; i < 4; i++)
#pragma unroll
    for (int j = 0; j < 4; j++)
#pragma unroll
      for (int r = 0; r < 4; r++) {
        const long gm = row0 + wm + i * 16 + kg * 4 + r;
        const long gn = col0 + wn + j * 16 + lm;
        if (gm < Nn && gn < Nn)
          C[gm * LDC + gn] = fmaf((float)acc[i][j][r], scale,
                                  0.5f * (sv[gm] + sv[gn]) + negq);
      }
}

// ---------------------------------------------------------------------------
// R [M,N] fp32 -> padded bf16 (for prop1) + centered-i8 plane (user gram)
// ---------------------------------------------------------------------------
__global__ __launch_bounds__(256) void pad_quant_kernel(
    const float* __restrict__ R, __bf16* __restrict__ H,
    signed char* __restrict__ Qp, int M, int N, int Np) {
  const int r = blockIdx.y;
  const int c = blockIdx.x * 256 + threadIdx.x;
  if (c >= Np) return;
  const bool in = (r < M && c < N);
  const float v = in ? R[(long)r * N + c] : 0.f;
  H[(long)r * Np + c] = (__bf16)v;
  Qp[(long)r * Np + c] =
      in ? (signed char)__float2int_rn((v - 0.5f) * 254.f) : (signed char)0;
}

// ---------------------------------------------------------------------------
// Transpose fp32 [M,N] -> padded centered-i8 [Np, Mp] (item gram), LDS-tiled.
// ---------------------------------------------------------------------------
__global__ __launch_bounds__(256) void transpose_quant_kernel(
    const float* __restrict__ R, signed char* __restrict__ Qp, int M, int N,
    int Mp, int Np) {
  __shared__ float tile[32][33];
  const int tx = threadIdx.x & 31;
  const int ty = threadIdx.x >> 5;
  const int ri = blockIdx.y * 32;
  const int ci = blockIdx.x * 32;
#pragma unroll
  for (int k = 0; k < 4; k++) {
    const int r = ri + ty + k * 8, c = ci + tx;
    tile[ty + k * 8][tx] = (r < M && c < N) ? R[(long)r * N + c] : 0.f;
  }
  __syncthreads();
#pragma unroll
  for (int k = 0; k < 4; k++) {
    const int orow = ci + ty + k * 8;
    const int ocol = ri + tx;
    if (orow < Np && ocol < Mp) {
      const bool in = (orow < N && ocol < M);
      const float v = tile[tx][ty + k * 8];
      Qp[(long)orow * Mp + ocol] =
          in ? (signed char)__float2int_rn((v - 0.5f) * 254.f) : (signed char)0;
    }
  }
}

// ---------------------------------------------------------------------------
// Mirror lower triangle of fp32 S [n,n] into strict upper, 32x32 tile pairs.
// ---------------------------------------------------------------------------
__global__ __launch_bounds__(256) void mirror_kernel(float* __restrict__ S,
                                                     int n) {
  __shared__ float tile[32][33];
  int by, bx;
  tri_decode(blockIdx.x, by, bx);
  const int tj = by + 1, ti = bx;  // tj > ti
  const int sr = tj * 32, sc = ti * 32;
  const int tx = threadIdx.x & 31;
  const int ty = threadIdx.x >> 5;
#pragma unroll
  for (int k = 0; k < 4; k++) {
    const int r = sr + ty + k * 8, c = sc + tx;
    tile[ty + k * 8][tx] = (r < n && c < n) ? S[(long)r * n + c] : 0.f;
  }
  __syncthreads();
#pragma unroll
  for (int k = 0; k < 4; k++) {
    const int r = sc + ty + k * 8, c = sr + tx;
    if (r < n && c < n) S[(long)r * n + c] = tile[tx][ty + k * 8];
  }
}

// ---------------------------------------------------------------------------
// norms + plain sums
// ---------------------------------------------------------------------------
__global__ __launch_bounds__(256) void row_norm_sum(
    const float* __restrict__ R, float* __restrict__ inv_n,
    float* __restrict__ sv, int M, int K) {
  __shared__ float redA[256];
  __shared__ float redB[256];
  const int row = blockIdx.x;
  float s2 = 0.f, s1 = 0.f;
  for (int j = threadIdx.x; j < K; j += 256) {
    const float v = R[(long)row * K + j];
    s2 = fmaf(v, v, s2);
    s1 += v;
  }
  redA[threadIdx.x] = s2;
  redB[threadIdx.x] = s1;
  __syncthreads();
  for (int o = 128; o > 0; o >>= 1) {
    if (threadIdx.x < o) {
      redA[threadIdx.x] += redA[threadIdx.x + o];
      redB[threadIdx.x] += redB[threadIdx.x + o];
    }
    __syncthreads();
  }
  if (threadIdx.x == 0) {
    inv_n[row] = 1.f / (sqrtf(redA[0]) + EPS);
    sv[row] = redB[0];
  }
}

// Column sums-of-squares + plain column sums, two-phase (coalesced).
__global__ __launch_bounds__(256) void col_sums_kernel(
    const float* __restrict__ R, float* __restrict__ acc2,
    float* __restrict__ acc1, int M, int N, int rows_per_chunk) {
  const int j = blockIdx.x * 256 + threadIdx.x;
  if (j >= N) return;
  const int r0 = blockIdx.y * rows_per_chunk;
  const int r1 = min(M, r0 + rows_per_chunk);
  float s2 = 0.f, s1 = 0.f;
  for (int i = r0; i < r1; i++) {
    const float v = R[(long)i * N + j];
    s2 = fmaf(v, v, s2);
    s1 += v;
  }
  atomicAdd(&acc2[j], s2);
  atomicAdd(&acc1[j], s1);
}

// inv_n[i] = 1/(sqrt(acc[i]) + EPS)
__global__ __launch_bounds__(256) void inv_norm_finalize(
    const float* __restrict__ acc, float* __restrict__ inv_n, int n) {
  const int i = blockIdx.x * 256 + threadIdx.x;
  if (i < n) inv_n[i] = 1.f / (sqrtf(acc[i]) + EPS);
}

// ---------------------------------------------------------------------------
// Top-k, one wave64 per row, ZERO LDS (verified round 6).
// ---------------------------------------------------------------------------
__global__ __launch_bounds__(64) void topk_kernel(
    float* __restrict__ G, const float* __restrict__ inv_n,
    __bf16* __restrict__ adj, float* __restrict__ rowsum,
    float* __restrict__ colsum, int n, int np, const int* __restrict__ kptr) {
  const int row = blockIdx.x;
  const int lane = threadIdx.x;
  const int k = *kptr;
  const float invr = inv_n[row];

  float v0 = -INFINITY, v1 = -INFINITY, v2 = -INFINITY, v3 = -INFINITY;
  int i0 = n, i1 = n, i2 = n, i3 = n;

  for (int j = lane; j < n; j += 64) {
    const float v =
        (j == row) ? -INFINITY : G[(long)row * n + j] * invr * inv_n[j];
    if (v > v3) {
      if (v > v1) {
        if (v > v0) {
          v3 = v2; i3 = i2; v2 = v1; i2 = i1; v1 = v0; i1 = i0; v0 = v; i0 = j;
        } else {
          v3 = v2; i3 = i2; v2 = v1; i2 = i1; v1 = v; i1 = j;
        }
      } else {
        if (v > v2) {
          v3 = v2; i3 = i2; v2 = v; i2 = j;
        } else {
          v3 = v; i3 = j;
        }
      }
    }
  }

  float rsum = 0.f;
  for (int t = 0; t < k; t++) {
    float v = v0;
    int i = i0;
#pragma unroll
    for (int off = 32; off > 0; off >>= 1) {
      const float ov = __shfl_xor(v, off);
      const int oi = __shfl_xor(i, off);
      if (ov > v || (ov == v && oi < i)) { v = ov; i = oi; }
    }
    if (lane == 0) {
      adj[(long)row * np + i] = (__bf16)v;
      atomicAdd(&colsum[i], v);
      rsum += v;
    }
    if ((i & 63) == lane) {
      G[(long)row * n + i] = -INFINITY;  // mark removed (my slice)
      v0 = v1; i0 = i1; v1 = v2; i1 = i2; v2 = v3; i2 = i3;
      v3 = -INFINITY; i3 = n;
      if (i0 == n) {  // list exhausted -> rare rescan of my slice
        for (int j = lane; j < n; j += 64) {
          const float vv =
              (j == row) ? -INFINITY : G[(long)row * n + j] * invr * inv_n[j];
          if (vv > v3) {
            if (vv > v1) {
              if (vv > v0) {
                v3 = v2; i3 = i2; v2 = v1; i2 = i1; v1 = v0; i1 = i0;
                v0 = vv; i0 = j;
              } else {
                v3 = v2; i3 = i2; v2 = v1; i2 = i1; v1 = vv; i1 = j;
              }
            } else {
              if (vv > v2) {
                v3 = v2; i3 = i2; v2 = vv; i2 = j;
              } else {
                v3 = vv; i3 = j;
              }
            }
          }
        }
      }
    }
  }
  if (lane == 0) rowsum[row] = rsum;
}

// f[i] = 1/sqrt(0.5*(rowsum+colsum) + EPS)
__global__ __launch_bounds__(256) void finalize_kernel(
    const float* __restrict__ rs, const float* __restrict__ cs,
    float* __restrict__ f, int n) {
  const int i = blockIdx.x * 256 + threadIdx.x;
  if (i < n) f[i] = rsqrtf(0.5f * (rs[i] + cs[i]) + EPS);
}

// in-place: adj[i,j] = adj[j,i] = 0.5*(adj[i,j]+adj[j,i]) * f[i]*f[j]
__global__ __launch_bounds__(256) void symscale_kernel(
    __bf16* __restrict__ adj, const float* __restrict__ f, int n, int np) {
  const long idx = (long)blockIdx.x * 256 + threadIdx.x;
  if (idx >= (long)np * np) return;
  const int i = (int)(idx / np);
  const int j = (int)(idx % np);
  if (j <= i || i >= n || j >= n) return;
  const float a = (float)adj[(long)i * np + j];
  const float b = (float)adj[(long)j * np + i];
  const float m = 0.5f * (a + b) * f[i] * f[j];
  adj[(long)i * np + j] = (__bf16)m;
  adj[(long)j * np + i] = (__bf16)m;
}

// ---------------------------------------------------------------------------
extern "C" void kernel_launch(void* const* d_in, const int* in_sizes, int n_in,
                              void* d_out, int out_size, void* d_ws,
                              size_t ws_size, hipStream_t stream) {
  const float* R = (const float*)d_in[0];
  const int* k_users_p = (const int*)d_in[1];
  const int* k_items_p = (const int*)d_in[2];
  float* out = (float*)d_out;
  const int NU = N_USERS, NI = N_ITEMS;

  // ---- workspace layout (round-3/6/7/8 verified; peak 328.4 MB) ----
  // Rh    [ 1.0,  50.3)  pad_quant -> prop1
  // Uh    [51.0,  75.7)  pad_quant -> user gram
  // Su    [77.0, 221.0)  user gram -> user topk   (written AFTER IhT/Si die)
  // IhT   [103., 127.7)  transpose -> item gram   (inside future-Su, ok)
  // Si    [128., 192.0)  item gram -> item topk   (inside future-Su, ok)
  // adjIb [222., 255.6)  item topk -> prop1
  // adjUb [256., 328.4)  user topk -> prop2
  // Tt    [77.0, 126.3)  prop1 -> prop2           (over dead Su)
  char* ws = (char*)d_ws;
  float* invNu = (float*)(ws + 0);        // 24 KB
  float* invNi = (float*)(ws + 32768);    // 16 KB
  float* rsU = (float*)(ws + 65536);      // 24 KB
  float* csU = (float*)(ws + 98304);      // 24 KB
  float* rsI = (float*)(ws + 131072);     // 16 KB
  float* csI = (float*)(ws + 163840);     // 16 KB
  float* fU = (float*)(ws + 196608);      // 24 KB
  float* fI = (float*)(ws + 229376);      // 16 KB
  float* nrmI = (float*)(ws + 262144);    // 16 KB (col sumsq accumulator)
  float* svU = (float*)(ws + 294912);     // 24 KB (row sums of R)
  float* svI = (float*)(ws + 327680);     // 16 KB (col sums of R)
  const long MB = 1000000L;
  __bf16* Rh = (__bf16*)(ws + 1 * MB);
  signed char* Uh = (signed char*)(ws + 51 * MB);
  float* Su = (float*)(ws + 77 * MB);
  signed char* IhT = (signed char*)(ws + 103 * MB);
  float* Si = (float*)(ws + 128 * MB);
  __bf16* adjIb = (__bf16*)(ws + 222 * MB);
  __bf16* adjUb = (__bf16*)(ws + 256 * MB);
  __bf16* Tt = (__bf16*)(ws + 77 * MB);

  // ---- norms + sums + quantized conversions ----
  row_norm_sum<<<NU, 256, 0, stream>>>(R, invNu, svU, NU, NI);
  hipMemsetAsync(nrmI, 0, NI * sizeof(float), stream);
  hipMemsetAsync(svI, 0, NI * sizeof(float), stream);
  col_sums_kernel<<<dim3((NI + 255) / 256, 60), 256, 0, stream>>>(R, nrmI, svI,
                                                                  NU, NI, 100);
  inv_norm_finalize<<<(NI + 255) / 256, 256, 0, stream>>>(nrmI, invNi, NI);
  pad_quant_kernel<<<dim3(NI_P / 256, NU_P), 256, 0, stream>>>(R, Rh, Uh, NU,
                                                               NI, NI_P);
  transpose_quant_kernel<<<dim3(NI_P / 32, NU_P / 32), 256, 0, stream>>>(
      R, IhT, NU, NI, NU_P, NI_P);

  // ================= item graph =================
  // S = G2/254^2 + 0.5*(svI[i]+svI[j]) - NU/4
  mfma_gram_i8<NU_P, NU_P, N_ITEMS><<<32 * 33 / 2, 256, 0, stream>>>(
      IhT, svI, Si, NI, -0.25f * (float)NU);
  {
    const int T = (NI + 31) / 32;  // 125
    mirror_kernel<<<T * (T - 1) / 2, 256, 0, stream>>>(Si, NI);
  }
  hipMemsetAsync(adjIb, 0, (long)NI_P * NI_P * sizeof(__bf16), stream);
  hipMemsetAsync(csI, 0, NI * sizeof(float), stream);
  topk_kernel<<<NI, 64, 0, stream>>>(Si, invNi, adjIb, rsI, csI, NI, NI_P,
                                     k_items_p);
  finalize_kernel<<<(NI + 255) / 256, 256, 0, stream>>>(rsI, csI, fI, NI);
  {
    const long tot = (long)NI_P * NI_P;
    symscale_kernel<<<(tot + 255) / 256, 256, 0, stream>>>(adjIb, fI, NI, NI_P);
  }

  // ================= user graph =================
  mfma_gram_i8<NI_P, NI_P, N_USERS><<<47 * 48 / 2, 256, 0, stream>>>(
      Uh, svU, Su, NU, -0.25f * (float)NI);
  {
    const int T = (NU + 31) / 32;  // 188
    mirror_kernel<<<T * (T - 1) / 2, 256, 0, stream>>>(Su, NU);
  }
  hipMemsetAsync(adjUb, 0, (long)NU_P * NU_P * sizeof(__bf16), stream);
  hipMemsetAsync(csU, 0, NU * sizeof(float), stream);
  topk_kernel<<<NU, 64, 0, stream>>>(Su, invNu, adjUb, rsU, csU, NU, NU_P,
                                     k_users_p);
  finalize_kernel<<<(NU + 255) / 256, 256, 0, stream>>>(rsU, csU, fU, NU);
  {
    const long tot = (long)NU_P * NU_P;
    symscale_kernel<<<(tot + 255) / 256, 256, 0, stream>>>(adjUb, fU, NU, NU_P);
  }

  // ================= propagation (bf16, verified) =================
  // prop1: Tt = T^T = adjI @ R^T  (bf16 out, full padded, over dead Su space)
  mfma_prop_bf16<NI_P, NI_P, NI_P, NU_P, 1><<<32 * 47, 256, 0, stream>>>(
      adjIb, Rh, nullptr, Tt, NI_P, NU_P, 32, 47);
  // prop2: out = adjU @ T = adjUb @ Tt^T
  mfma_prop_bf16<NU_P, NU_P, NU_P, N_ITEMS, 0><<<47 * 32, 256, 0, stream>>>(
      adjUb, Tt, out, nullptr, NU, NI, 47, 32);
}

// Round 10
// 1711.007 us; speedup vs baseline: 1.1807x; 1.1807x over previous
//
#include <hip/hip_runtime.h>
#include <math.h>

#define EPS 1e-8f

constexpr int N_USERS = 6000;
constexpr int N_ITEMS = 4000;
constexpr int NU_P = 6016;  // 47 * 128
constexpr int NI_P = 4096;  // 32 * 128

typedef __bf16 bf16_8 __attribute__((ext_vector_type(8)));
typedef float f32_4 __attribute__((ext_vector_type(4)));
typedef int i32x4 __attribute__((ext_vector_type(4)));

// ---------------------------------------------------------------------------
__device__ __forceinline__ void stage16(const void* g, void* l) {
  __builtin_amdgcn_global_load_lds(
      (const __attribute__((address_space(1))) void*)g,
      (__attribute__((address_space(3))) void*)l, 16, 0, 0);
}

// XCD-aware bijective swizzle (requires nwg % 8 == 0; all MFMA grids are).
__device__ __forceinline__ int xcd_swz(int p, int nwg) {
  return (p & 7) * (nwg >> 3) + (p >> 3);
}

// triangular decode: p -> (by, bx) with bx <= by
__device__ __forceinline__ void tri_decode(int p, int& by, int& bx) {
  int r = (int)((sqrtf(8.f * p + 1.f) - 1.f) * 0.5f);
  while ((r + 1) * (r + 2) / 2 <= p) r++;
  while (r * (r + 1) / 2 > p) r--;
  by = r;
  bx = p - r * (r + 1) / 2;
}

// grouped decode (G=8 rows, column-major within band) for L2 locality
__device__ __forceinline__ void grp_decode(int p, int nby, int nbx, int& by,
                                           int& bx) {
  const int G = 8;
  const int wide = G * nbx;
  const int band = p / wide;
  const int rem = p - band * wide;
  const int h = min(G, nby - band * G);
  by = band * G + rem % h;
  bx = rem / h;
}

// ---------------------------------------------------------------------------
// bf16 prop GEMM — ROUND-7 KERNEL VERBATIM (measured 376 us, the empirical
// optimum of the 128^2 structure: batch 8 stages -> one vmcnt drain per 64-K
// -> 32 MFMA. Interleaved prefetch variants (r8 runtime-idx, r9 static-idx
// unrolled) both regressed: per-chunk drain exposure + VGPR pressure).
// ---------------------------------------------------------------------------
template <int KK, int LDA, int LDB, int LDC, int OUTBF16>
__global__ __launch_bounds__(256) void mfma_prop_bf16(
    const __bf16* __restrict__ A, const __bf16* __restrict__ B,
    float* __restrict__ Cf, __bf16* __restrict__ Cb, int M, int N, int nby,
    int nbx) {
  __shared__ __bf16 sA[2][128 * 32];
  __shared__ __bf16 sB[2][128 * 32];

  int by, bx;
  grp_decode(xcd_swz(blockIdx.x, gridDim.x), nby, nbx, by, bx);

  const int tid = threadIdx.x;
  const int lane = tid & 63;
  const int wave = tid >> 6;
  const int wm = (wave >> 1) * 64;
  const int wn = (wave & 1) * 64;
  const int lm = lane & 15;
  const int kg = lane >> 4;
  const long row0 = (long)by * 128;
  const long col0 = (long)bx * 128;

  f32_4 acc[4][4];
#pragma unroll
  for (int i = 0; i < 4; i++)
#pragma unroll
    for (int j = 0; j < 4; j++) acc[i][j] = (f32_4){0.f, 0.f, 0.f, 0.f};

  const int c0 = tid, c1 = tid + 256;
  const int r0c = c0 >> 2, j0c = ((c0 & 3) - (r0c >> 1)) & 3;
  const int r1c = c1 >> 2, j1c = ((c1 & 3) - (r1c >> 1)) & 3;

  // loop-invariant fragment offsets (elements)
  int offA[4], offB[4];
#pragma unroll
  for (int i = 0; i < 4; i++) {
    const int ra = wm + i * 16 + lm;
    const int rb = wn + i * 16 + lm;
    offA[i] = (ra * 4 + ((kg + (ra >> 1)) & 3)) * 8;
    offB[i] = (rb * 4 + ((kg + (rb >> 1)) & 3)) * 8;
  }

  const __bf16* a0 = A + (row0 + r0c) * LDA + j0c * 8;
  const __bf16* a1 = A + (row0 + r1c) * LDA + j1c * 8;
  const __bf16* b0 = B + (col0 + r0c) * LDB + j0c * 8;
  const __bf16* b1 = B + (col0 + r1c) * LDB + j1c * 8;

  for (int k0 = 0; k0 < KK; k0 += 64) {
    stage16(a0 + k0, &sA[0][c0 * 8]);
    stage16(a1 + k0, &sA[0][c1 * 8]);
    stage16(b0 + k0, &sB[0][c0 * 8]);
    stage16(b1 + k0, &sB[0][c1 * 8]);
    stage16(a0 + k0 + 32, &sA[1][c0 * 8]);
    stage16(a1 + k0 + 32, &sA[1][c1 * 8]);
    stage16(b0 + k0 + 32, &sB[1][c0 * 8]);
    stage16(b1 + k0 + 32, &sB[1][c1 * 8]);
    __syncthreads();

#pragma unroll
    for (int h = 0; h < 2; h++) {
      bf16_8 a[4], b[4];
#pragma unroll
      for (int i = 0; i < 4; i++) {
        a[i] = *(const bf16_8*)&sA[h][offA[i]];
        b[i] = *(const bf16_8*)&sB[h][offB[i]];
      }
#pragma unroll
      for (int i = 0; i < 4; i++)
#pragma unroll
        for (int j = 0; j < 4; j++)
          acc[i][j] = __builtin_amdgcn_mfma_f32_16x16x32_bf16(a[i], b[j],
                                                              acc[i][j], 0, 0,
                                                              0);
    }
    __syncthreads();
  }

  // epilogue: C/D layout col=lane&15, row=(lane>>4)*4+reg
#pragma unroll
  for (int i = 0; i < 4; i++)
#pragma unroll
    for (int j = 0; j < 4; j++)
#pragma unroll
      for (int r = 0; r < 4; r++) {
        const long gm = row0 + wm + i * 16 + kg * 4 + r;
        const long gn = col0 + wn + j * 16 + lm;
        if (gm < M && gn < N) {
          if (OUTBF16)
            Cb[gm * LDC + gn] = (__bf16)acc[i][j][r];
          else
            Cf[gm * LDC + gn] = acc[i][j][r];
        }
      }
}

// ---------------------------------------------------------------------------
// Single-plane centered-i8 GRAM — ROUND-6 SCHEDULE (single 16 KB buffers,
// BK=64: stage 4 -> drain -> 16 MFMA -> barrier; best measured non-prop
// aggregate) + compile-time strides/hoisted offsets (the one change proven
// beneficial in isolation on the props: VALU 55->24%). Math verified r3/r6.
// ---------------------------------------------------------------------------
template <int KK, int LD, int LDC>
__global__ __launch_bounds__(256) void mfma_gram_i8(
    const signed char* __restrict__ Q, const float* __restrict__ sv,
    float* __restrict__ C, int Nn, float negq) {
  __shared__ signed char sA[128 * 64];
  __shared__ signed char sB[128 * 64];

  int by, bx;
  tri_decode(xcd_swz(blockIdx.x, gridDim.x), by, bx);

  const int tid = threadIdx.x;
  const int lane = tid & 63;
  const int wave = tid >> 6;
  const int wm = (wave >> 1) * 64;
  const int wn = (wave & 1) * 64;
  const int lm = lane & 15;
  const int kg = lane >> 4;
  const long row0 = (long)by * 128;
  const long col0 = (long)bx * 128;
  const float scale = 1.f / (254.f * 254.f);

  i32x4 acc[4][4];
#pragma unroll
  for (int i = 0; i < 4; i++)
#pragma unroll
    for (int j = 0; j < 4; j++) acc[i][j] = (i32x4){0, 0, 0, 0};

  const int c0 = tid, c1 = tid + 256;
  const int r0c = c0 >> 2, j0c = ((c0 & 3) - (r0c >> 1)) & 3;
  const int r1c = c1 >> 2, j1c = ((c1 & 3) - (r1c >> 1)) & 3;

  int offA[4], offB[4];
#pragma unroll
  for (int i = 0; i < 4; i++) {
    const int ra = wm + i * 16 + lm;
    const int rb = wn + i * 16 + lm;
    offA[i] = (ra * 4 + ((kg + (ra >> 1)) & 3)) * 16;
    offB[i] = (rb * 4 + ((kg + (rb >> 1)) & 3)) * 16;
  }

  const signed char* a0 = Q + (row0 + r0c) * LD + j0c * 16;
  const signed char* a1 = Q + (row0 + r1c) * LD + j1c * 16;
  const signed char* b0 = Q + (col0 + r0c) * LD + j0c * 16;
  const signed char* b1 = Q + (col0 + r1c) * LD + j1c * 16;

  for (int k0 = 0; k0 < KK; k0 += 64) {
    stage16(a0 + k0, &sA[c0 * 16]);
    stage16(a1 + k0, &sA[c1 * 16]);
    stage16(b0 + k0, &sB[c0 * 16]);
    stage16(b1 + k0, &sB[c1 * 16]);
    __syncthreads();

    i32x4 a[4], b[4];
#pragma unroll
    for (int i = 0; i < 4; i++) {
      a[i] = *(const i32x4*)&sA[offA[i]];
      b[i] = *(const i32x4*)&sB[offB[i]];
    }
#pragma unroll
    for (int i = 0; i < 4; i++)
#pragma unroll
      for (int j = 0; j < 4; j++)
        acc[i][j] = __builtin_amdgcn_mfma_i32_16x16x64_i8(a[i], b[j],
                                                          acc[i][j], 0, 0, 0);
    __syncthreads();
  }

#pragma unroll
  for (int i = 0; i < 4; i++)
#pragma unroll
    for (int j = 0; j < 4; j++)
#pragma unroll
      for (int r = 0; r < 4; r++) {
        const long gm = row0 + wm + i * 16 + kg * 4 + r;
        const long gn = col0 + wn + j * 16 + lm;
        if (gm < Nn && gn < Nn)
          C[gm * LDC + gn] = fmaf((float)acc[i][j][r], scale,
                                  0.5f * (sv[gm] + sv[gn]) + negq);
      }
}

// ---------------------------------------------------------------------------
// R [M,N] fp32 -> padded bf16 (for prop1) + centered-i8 plane (user gram)
// ---------------------------------------------------------------------------
__global__ __launch_bounds__(256) void pad_quant_kernel(
    const float* __restrict__ R, __bf16* __restrict__ H,
    signed char* __restrict__ Qp, int M, int N, int Np) {
  const int r = blockIdx.y;
  const int c = blockIdx.x * 256 + threadIdx.x;
  if (c >= Np) return;
  const bool in = (r < M && c < N);
  const float v = in ? R[(long)r * N + c] : 0.f;
  H[(long)r * Np + c] = (__bf16)v;
  Qp[(long)r * Np + c] =
      in ? (signed char)__float2int_rn((v - 0.5f) * 254.f) : (signed char)0;
}

// ---------------------------------------------------------------------------
// Transpose fp32 [M,N] -> padded centered-i8 [Np, Mp] (item gram), LDS-tiled.
// ---------------------------------------------------------------------------
__global__ __launch_bounds__(256) void transpose_quant_kernel(
    const float* __restrict__ R, signed char* __restrict__ Qp, int M, int N,
    int Mp, int Np) {
  __shared__ float tile[32][33];
  const int tx = threadIdx.x & 31;
  const int ty = threadIdx.x >> 5;
  const int ri = blockIdx.y * 32;
  const int ci = blockIdx.x * 32;
#pragma unroll
  for (int k = 0; k < 4; k++) {
    const int r = ri + ty + k * 8, c = ci + tx;
    tile[ty + k * 8][tx] = (r < M && c < N) ? R[(long)r * N + c] : 0.f;
  }
  __syncthreads();
#pragma unroll
  for (int k = 0; k < 4; k++) {
    const int orow = ci + ty + k * 8;
    const int ocol = ri + tx;
    if (orow < Np && ocol < Mp) {
      const bool in = (orow < N && ocol < M);
      const float v = tile[tx][ty + k * 8];
      Qp[(long)orow * Mp + ocol] =
          in ? (signed char)__float2int_rn((v - 0.5f) * 254.f) : (signed char)0;
    }
  }
}

// ---------------------------------------------------------------------------
// Mirror lower triangle of fp32 S [n,n] into strict upper, 32x32 tile pairs.
// ---------------------------------------------------------------------------
__global__ __launch_bounds__(256) void mirror_kernel(float* __restrict__ S,
                                                     int n) {
  __shared__ float tile[32][33];
  int by, bx;
  tri_decode(blockIdx.x, by, bx);
  const int tj = by + 1, ti = bx;  // tj > ti
  const int sr = tj * 32, sc = ti * 32;
  const int tx = threadIdx.x & 31;
  const int ty = threadIdx.x >> 5;
#pragma unroll
  for (int k = 0; k < 4; k++) {
    const int r = sr + ty + k * 8, c = sc + tx;
    tile[ty + k * 8][tx] = (r < n && c < n) ? S[(long)r * n + c] : 0.f;
  }
  __syncthreads();
#pragma unroll
  for (int k = 0; k < 4; k++) {
    const int r = sc + ty + k * 8, c = sr + tx;
    if (r < n && c < n) S[(long)r * n + c] = tile[tx][ty + k * 8];
  }
}

// ---------------------------------------------------------------------------
// norms + plain sums
// ---------------------------------------------------------------------------
__global__ __launch_bounds__(256) void row_norm_sum(
    const float* __restrict__ R, float* __restrict__ inv_n,
    float* __restrict__ sv, int M, int K) {
  __shared__ float redA[256];
  __shared__ float redB[256];
  const int row = blockIdx.x;
  float s2 = 0.f, s1 = 0.f;
  for (int j = threadIdx.x; j < K; j += 256) {
    const float v = R[(long)row * K + j];
    s2 = fmaf(v, v, s2);
    s1 += v;
  }
  redA[threadIdx.x] = s2;
  redB[threadIdx.x] = s1;
  __syncthreads();
  for (int o = 128; o > 0; o >>= 1) {
    if (threadIdx.x < o) {
      redA[threadIdx.x] += redA[threadIdx.x + o];
      redB[threadIdx.x] += redB[threadIdx.x + o];
    }
    __syncthreads();
  }
  if (threadIdx.x == 0) {
    inv_n[row] = 1.f / (sqrtf(redA[0]) + EPS);
    sv[row] = redB[0];
  }
}

// Column sums-of-squares + plain column sums, two-phase (coalesced).
__global__ __launch_bounds__(256) void col_sums_kernel(
    const float* __restrict__ R, float* __restrict__ acc2,
    float* __restrict__ acc1, int M, int N, int rows_per_chunk) {
  const int j = blockIdx.x * 256 + threadIdx.x;
  if (j >= N) return;
  const int r0 = blockIdx.y * rows_per_chunk;
  const int r1 = min(M, r0 + rows_per_chunk);
  float s2 = 0.f, s1 = 0.f;
  for (int i = r0; i < r1; i++) {
    const float v = R[(long)i * N + j];
    s2 = fmaf(v, v, s2);
    s1 += v;
  }
  atomicAdd(&acc2[j], s2);
  atomicAdd(&acc1[j], s1);
}

// inv_n[i] = 1/(sqrt(acc[i]) + EPS)
__global__ __launch_bounds__(256) void inv_norm_finalize(
    const float* __restrict__ acc, float* __restrict__ inv_n, int n) {
  const int i = blockIdx.x * 256 + threadIdx.x;
  if (i < n) inv_n[i] = 1.f / (sqrtf(acc[i]) + EPS);
}

// ---------------------------------------------------------------------------
// Top-k, one wave64 per row, ZERO LDS (verified round 6).
// ---------------------------------------------------------------------------
__global__ __launch_bounds__(64) void topk_kernel(
    float* __restrict__ G, const float* __restrict__ inv_n,
    __bf16* __restrict__ adj, float* __restrict__ rowsum,
    float* __restrict__ colsum, int n, int np, const int* __restrict__ kptr) {
  const int row = blockIdx.x;
  const int lane = threadIdx.x;
  const int k = *kptr;
  const float invr = inv_n[row];

  float v0 = -INFINITY, v1 = -INFINITY, v2 = -INFINITY, v3 = -INFINITY;
  int i0 = n, i1 = n, i2 = n, i3 = n;

  for (int j = lane; j < n; j += 64) {
    const float v =
        (j == row) ? -INFINITY : G[(long)row * n + j] * invr * inv_n[j];
    if (v > v3) {
      if (v > v1) {
        if (v > v0) {
          v3 = v2; i3 = i2; v2 = v1; i2 = i1; v1 = v0; i1 = i0; v0 = v; i0 = j;
        } else {
          v3 = v2; i3 = i2; v2 = v1; i2 = i1; v1 = v; i1 = j;
        }
      } else {
        if (v > v2) {
          v3 = v2; i3 = i2; v2 = v; i2 = j;
        } else {
          v3 = v; i3 = j;
        }
      }
    }
  }

  float rsum = 0.f;
  for (int t = 0; t < k; t++) {
    float v = v0;
    int i = i0;
#pragma unroll
    for (int off = 32; off > 0; off >>= 1) {
      const float ov = __shfl_xor(v, off);
      const int oi = __shfl_xor(i, off);
      if (ov > v || (ov == v && oi < i)) { v = ov; i = oi; }
    }
    if (lane == 0) {
      adj[(long)row * np + i] = (__bf16)v;
      atomicAdd(&colsum[i], v);
      rsum += v;
    }
    if ((i & 63) == lane) {
      G[(long)row * n + i] = -INFINITY;  // mark removed (my slice)
      v0 = v1; i0 = i1; v1 = v2; i1 = i2; v2 = v3; i2 = i3;
      v3 = -INFINITY; i3 = n;
      if (i0 == n) {  // list exhausted -> rare rescan of my slice
        for (int j = lane; j < n; j += 64) {
          const float vv =
              (j == row) ? -INFINITY : G[(long)row * n + j] * invr * inv_n[j];
          if (vv > v3) {
            if (vv > v1) {
              if (vv > v0) {
                v3 = v2; i3 = i2; v2 = v1; i2 = i1; v1 = v0; i1 = i0;
                v0 = vv; i0 = j;
              } else {
                v3 = v2; i3 = i2; v2 = v1; i2 = i1; v1 = vv; i1 = j;
              }
            } else {
              if (vv > v2) {
                v3 = v2; i3 = i2; v2 = vv; i2 = j;
              } else {
                v3 = vv; i3 = j;
              }
            }
          }
        }
      }
    }
  }
  if (lane == 0) rowsum[row] = rsum;
}

// f[i] = 1/sqrt(0.5*(rowsum+colsum) + EPS)
__global__ __launch_bounds__(256) void finalize_kernel(
    const float* __restrict__ rs, const float* __restrict__ cs,
    float* __restrict__ f, int n) {
  const int i = blockIdx.x * 256 + threadIdx.x;
  if (i < n) f[i] = rsqrtf(0.5f * (rs[i] + cs[i]) + EPS);
}

// in-place: adj[i,j] = adj[j,i] = 0.5*(adj[i,j]+adj[j,i]) * f[i]*f[j]
// 2D grid (i = blockIdx.y): same per-element arithmetic as the verified
// linear version, without the 64-bit div/mod per thread.
__global__ __launch_bounds__(256) void symscale_kernel(
    __bf16* __restrict__ adj, const float* __restrict__ f, int n, int np) {
  const int i = blockIdx.y;
  const int j = blockIdx.x * 256 + threadIdx.x;
  if (j >= np || j <= i || i >= n || j >= n) return;
  const float a = (float)adj[(long)i * np + j];
  const float b = (float)adj[(long)j * np + i];
  const float m = 0.5f * (a + b) * f[i] * f[j];
  adj[(long)i * np + j] = (__bf16)m;
  adj[(long)j * np + i] = (__bf16)m;
}

// ---------------------------------------------------------------------------
extern "C" void kernel_launch(void* const* d_in, const int* in_sizes, int n_in,
                              void* d_out, int out_size, void* d_ws,
                              size_t ws_size, hipStream_t stream) {
  const float* R = (const float*)d_in[0];
  const int* k_users_p = (const int*)d_in[1];
  const int* k_items_p = (const int*)d_in[2];
  float* out = (float*)d_out;
  const int NU = N_USERS, NI = N_ITEMS;

  // ---- workspace layout (round-3/6/7 verified; peak 328.4 MB) ----
  // Rh    [ 1.0,  50.3)  pad_quant -> prop1
  // Uh    [51.0,  75.7)  pad_quant -> user gram
  // Su    [77.0, 221.0)  user gram -> user topk   (written AFTER IhT/Si die)
  // IhT   [103., 127.7)  transpose -> item gram   (inside future-Su, ok)
  // Si    [128., 192.0)  item gram -> item topk   (inside future-Su, ok)
  // adjIb [222., 255.6)  item topk -> prop1
  // adjUb [256., 328.4)  user topk -> prop2
  // Tt    [77.0, 126.3)  prop1 -> prop2           (over dead Su)
  char* ws = (char*)d_ws;
  float* invNu = (float*)(ws + 0);        // 24 KB
  float* invNi = (float*)(ws + 32768);    // 16 KB
  float* rsU = (float*)(ws + 65536);      // 24 KB
  float* csU = (float*)(ws + 98304);      // 24 KB
  float* rsI = (float*)(ws + 131072);     // 16 KB
  float* csI = (float*)(ws + 163840);     // 16 KB
  float* fU = (float*)(ws + 196608);      // 24 KB
  float* fI = (float*)(ws + 229376);      // 16 KB
  float* nrmI = (float*)(ws + 262144);    // 16 KB (col sumsq accumulator)
  float* svU = (float*)(ws + 294912);     // 24 KB (row sums of R)
  float* svI = (float*)(ws + 327680);     // 16 KB (col sums of R)
  const long MB = 1000000L;
  __bf16* Rh = (__bf16*)(ws + 1 * MB);
  signed char* Uh = (signed char*)(ws + 51 * MB);
  float* Su = (float*)(ws + 77 * MB);
  signed char* IhT = (signed char*)(ws + 103 * MB);
  float* Si = (float*)(ws + 128 * MB);
  __bf16* adjIb = (__bf16*)(ws + 222 * MB);
  __bf16* adjUb = (__bf16*)(ws + 256 * MB);
  __bf16* Tt = (__bf16*)(ws + 77 * MB);

  // ---- norms + sums + quantized conversions ----
  row_norm_sum<<<NU, 256, 0, stream>>>(R, invNu, svU, NU, NI);
  hipMemsetAsync(nrmI, 0, NI * sizeof(float), stream);
  hipMemsetAsync(svI, 0, NI * sizeof(float), stream);
  col_sums_kernel<<<dim3((NI + 255) / 256, 60), 256, 0, stream>>>(R, nrmI, svI,
                                                                  NU, NI, 100);
  inv_norm_finalize<<<(NI + 255) / 256, 256, 0, stream>>>(nrmI, invNi, NI);
  pad_quant_kernel<<<dim3(NI_P / 256, NU_P), 256, 0, stream>>>(R, Rh, Uh, NU,
                                                               NI, NI_P);
  transpose_quant_kernel<<<dim3(NI_P / 32, NU_P / 32), 256, 0, stream>>>(
      R, IhT, NU, NI, NU_P, NI_P);

  // ================= item graph =================
  // S = G2/254^2 + 0.5*(svI[i]+svI[j]) - NU/4
  mfma_gram_i8<NU_P, NU_P, N_ITEMS><<<32 * 33 / 2, 256, 0, stream>>>(
      IhT, svI, Si, NI, -0.25f * (float)NU);
  {
    const int T = (NI + 31) / 32;  // 125
    mirror_kernel<<<T * (T - 1) / 2, 256, 0, stream>>>(Si, NI);
  }
  hipMemsetAsync(adjIb, 0, (long)NI_P * NI_P * sizeof(__bf16), stream);
  hipMemsetAsync(csI, 0, NI * sizeof(float), stream);
  topk_kernel<<<NI, 64, 0, stream>>>(Si, invNi, adjIb, rsI, csI, NI, NI_P,
                                     k_items_p);
  finalize_kernel<<<(NI + 255) / 256, 256, 0, stream>>>(rsI, csI, fI, NI);
  symscale_kernel<<<dim3((NI_P + 255) / 256, NI_P), 256, 0, stream>>>(
      adjIb, fI, NI, NI_P);

  // ================= user graph =================
  mfma_gram_i8<NI_P, NI_P, N_USERS><<<47 * 48 / 2, 256, 0, stream>>>(
      Uh, svU, Su, NU, -0.25f * (float)NI);
  {
    const int T = (NU + 31) / 32;  // 188
    mirror_kernel<<<T * (T - 1) / 2, 256, 0, stream>>>(Su, NU);
  }
  hipMemsetAsync(adjUb, 0, (long)NU_P * NU_P * sizeof(__bf16), stream);
  hipMemsetAsync(csU, 0, NU * sizeof(float), stream);
  topk_kernel<<<NU, 64, 0, stream>>>(Su, invNu, adjUb, rsU, csU, NU, NU_P,
                                     k_users_p);
  finalize_kernel<<<(NU + 255) / 256, 256, 0, stream>>>(rsU, csU, fU, NU);
  symscale_kernel<<<dim3((NU_P + 255) / 256, NU_P), 256, 0, stream>>>(
      adjUb, fU, NU, NU_P);

  // ================= propagation (bf16, verified) =================
  // prop1: Tt = T^T = adjI @ R^T  (bf16 out, full padded, over dead Su space)
  mfma_prop_bf16<NI_P, NI_P, NI_P, NU_P, 1><<<32 * 47, 256, 0, stream>>>(
      adjIb, Rh, nullptr, Tt, NI_P, NU_P, 32, 47);
  // prop2: out = adjU @ T = adjUb @ Tt^T
  mfma_prop_bf16<NU_P, NU_P, NU_P, N_ITEMS, 0><<<47 * 32, 256, 0, stream>>>(
      adjUb, Tt, out, nullptr, NU, NI, 47, 32);
}